// Round 9
// baseline (124.897 us; speedup 1.0000x reference)
//
#include <hip/hip_runtime.h>
#include <hip/hip_bf16.h>

typedef __attribute__((ext_vector_type(8))) short short8;
typedef __attribute__((ext_vector_type(8))) __bf16 bf16x8;
typedef __attribute__((ext_vector_type(4))) float f32x4;

#define MFMA(a, b, c) __builtin_amdgcn_mfma_f32_16x16x32_bf16((a), (b), (c), 0, 0, 0)
#define SCALE 0.0625f

static __device__ __forceinline__ void gload16(const void* g, void* l) {
  __builtin_amdgcn_global_load_lds(
      (const __attribute__((address_space(1))) void*)g,
      (__attribute__((address_space(3))) void*)l, 16, 0, 0);
}

static __device__ __forceinline__ unsigned short f2b(float f) {
  union { __hip_bfloat16 h; unsigned short u; } cv;
  cv.h = __float2bfloat16(f);
  return cv.u;
}

// ---- x (f32) -> bf16, 8 elems/thread ---------------------------------------
__global__ __launch_bounds__(256) void convert_x_kern(const float* __restrict__ x,
                                                      unsigned short* __restrict__ xb) {
  long i = ((long)blockIdx.x * 256 + threadIdx.x) * 8;
  float4 a = *reinterpret_cast<const float4*>(x + i);
  float4 b = *reinterpret_cast<const float4*>(x + i + 4);
  short8 o;
  o[0] = (short)f2b(a.x); o[1] = (short)f2b(a.y); o[2] = (short)f2b(a.z); o[3] = (short)f2b(a.w);
  o[4] = (short)f2b(b.x); o[5] = (short)f2b(b.y); o[6] = (short)f2b(b.z); o[7] = (short)f2b(b.w);
  *reinterpret_cast<short8*>(xb + i) = o;
}

// ---- pack biases into one [1536] f32 buffer --------------------------------
__global__ void pack_bias_kern(const float* __restrict__ bq, const float* __restrict__ bk,
                               const float* __restrict__ bv, float* __restrict__ bc) {
  int i = blockIdx.x * 256 + threadIdx.x;
  float v = (i < 256) ? bq[i] : (i < 512) ? bk[i - 256] : bv[i - 512];
  bc[i] = v;
}

// ---- transpose f32 [R][C] -> bf16 [C][R], 64x64 tiles ----------------------
__global__ __launch_bounds__(256) void transpose_w_kern(const float* __restrict__ src,
                                                        unsigned short* __restrict__ dst,
                                                        int ldsrc, int lddst) {
  __shared__ __align__(16) unsigned short tile[64][72];
  int r0 = blockIdx.y * 64, c0 = blockIdx.x * 64;
  int t = threadIdx.x;
  #pragma unroll
  for (int it = 0; it < 4; ++it) {
    int idx = it * 1024 + t * 4;
    int row = idx >> 6, col = idx & 63;
    float4 v = *reinterpret_cast<const float4*>(src + (long)(r0 + row) * ldsrc + c0 + col);
    tile[row][col + 0] = f2b(v.x); tile[row][col + 1] = f2b(v.y);
    tile[row][col + 2] = f2b(v.z); tile[row][col + 3] = f2b(v.w);
  }
  __syncthreads();
  #pragma unroll
  for (int it = 0; it < 4; ++it) {
    int idx = it * 1024 + t * 4;
    int orow = idx >> 6, ocol = idx & 63;
    ushort4 o;
    o.x = tile[ocol + 0][orow]; o.y = tile[ocol + 1][orow];
    o.z = tile[ocol + 2][orow]; o.w = tile[ocol + 3][orow];
    *reinterpret_cast<ushort4*>(dst + (long)(c0 + orow) * lddst + r0 + ocol) = o;
  }
}

// ---- transpose bf16 [R][C] -> [C][R], batched (for V) ----------------------
__global__ __launch_bounds__(256) void transpose_v_kern(const unsigned short* __restrict__ src0,
                                                        unsigned short* __restrict__ dst0,
                                                        int ldsrc, int lddst,
                                                        long sbatch, long dbatch) {
  const unsigned short* src = src0 + (long)blockIdx.z * sbatch;
  unsigned short* dst = dst0 + (long)blockIdx.z * dbatch;
  __shared__ __align__(16) unsigned short tile[64][72];
  int r0 = blockIdx.y * 64, c0 = blockIdx.x * 64;
  int t = threadIdx.x;
  #pragma unroll
  for (int it = 0; it < 2; ++it) {
    int idx = it * 2048 + t * 8;
    int row = idx >> 6, col = idx & 63;
    short8 v = *reinterpret_cast<const short8*>(src + (long)(r0 + row) * ldsrc + c0 + col);
    *reinterpret_cast<short8*>(&tile[row][col]) = v;
  }
  __syncthreads();
  #pragma unroll
  for (int it = 0; it < 2; ++it) {
    int idx = it * 2048 + t * 8;
    int orow = idx >> 6, ocol = idx & 63;
    short8 o;
    #pragma unroll
    for (int i = 0; i < 8; ++i) o[i] = (short)tile[ocol + i][orow];
    *reinterpret_cast<short8*>(dst + (long)(c0 + orow) * lddst + r0 + ocol) = o;
  }
}

// ============================================================================
// gemm_tb ("thin block"): C[M][N] = A[M][K] * B[N][K]^T.
// BM=256, BN=128, BK=32. 256 threads = 4 waves (2M x 2N); wave tile 128x64:
// 12 ds_read_b128 per 32 MFMA (0.375 ratio, m201-class). 3-buffer LDS
// (3 x 24KB = 72KB) -> 2 blocks/CU: the sibling block's MFMA bursts hide
// this block's barrier/lgkm drains (m97 implicit-overlap mechanism).
// Per K-tile: {issue 12 reads | stage tile t+2 (6 gload16) -> s_barrier ->
// lgkmcnt(0)+sched_barrier -> setprio(1) 32 MFMA setprio(0) -> counted
// vmcnt -> s_barrier}. vmcnt(6) retires tile t+1 (6 loads/thread/tile,
// r4-proven discipline; NT-2 -> vmcnt(0)).
// 64B LDS rows; swizzle slot = chunk ^ ((row>>2)&3) (16B granular): lanes
// {c,c+4,c+8,c+12} land on 4 distinct slots (conflict-free), {c,c+2} worst
// 2-way (free per m136). Inverse applied on global source (rule #21).
// SWZ maps: 0=QKV (384 blk, tm-affinity per XCD), 1=PV (256 blk, batch ->
// XCD pair), 2=score (512 blk, batch -> XCD pair, EXPSUM epilogue).
// ============================================================================
template <int SWZ, bool BF16OUT, bool BIAS, bool RS, bool EXPSUM>
__global__ __launch_bounds__(256, 2) void gemm_tb(
    const unsigned short* __restrict__ A, const unsigned short* __restrict__ B,
    const float* __restrict__ bias, void* __restrict__ Cout,
    int NT, int lda, int ldb, int ldc,
    long batchA, long batchB, long batchC,
    const float* __restrict__ rowscale,
    float* __restrict__ lpart) {
  constexpr int ASH = 256 * 32;           // 8192 shorts (16KB)
  constexpr int BSH = 128 * 32;           // 4096 shorts (8KB)
  constexpr int TSH = ASH + BSH;          // 24KB
  __shared__ __align__(128) unsigned short lds[3 * TSH];

  int bid = blockIdx.x;
  int b = 0, tm, tn;
  if constexpr (SWZ == 0) {               // QKV: 384 = 8 xcd * 48 (4tm x 12tn)
    int xcd = bid & 7, s = bid >> 3;
    tm = xcd * 4 + s / 12; tn = s % 12;
  } else if constexpr (SWZ == 1) {        // PV: 256 = 8 xcd * 32 (4tm x 8tn)
    int xcd = bid & 7, s = bid >> 3;
    b = xcd >> 1; tm = (xcd & 1) * 4 + (s >> 3); tn = s & 7;
  } else {                                // score: 512 = 8 xcd * 64 (4tm x 16tn)
    int xcd = bid & 7, s = bid >> 3;
    b = xcd >> 1; tm = (xcd & 1) * 4 + (s >> 4); tn = s & 15;
  }

  int t = threadIdx.x, w = t >> 6, l = t & 63;
  int wr = w >> 1, wc = w & 1;            // 2 x 2 wave grid
  int g = l >> 4, c = l & 15;

  f32x4 acc[8][4];
  #pragma unroll
  for (int m = 0; m < 8; ++m)
    #pragma unroll
    for (int n = 0; n < 4; ++n) acc[m][n] = (f32x4){0.f, 0.f, 0.f, 0.f};

  const unsigned short* aptr = A + (long)b * batchA + (long)(tm * 256) * lda;
  const unsigned short* bptr = B + (long)b * batchB + (long)(tn * 128) * ldb;

  int srow = t >> 2;                      // 0..63 (row within 64-row round)
  int sch = t & 3;                        // 16B chunk within 64B row

  auto stageA = [&](int buf, int k0, int r) {
    int row = r * 64 + srow;
    int ch = sch ^ ((row >> 2) & 3);      // inverse-swizzled source
    gload16(aptr + (long)row * lda + k0 + ch * 8,
            lds + buf * TSH + r * 2048 + t * 8);
  };
  auto stageB = [&](int buf, int k0, int r) {
    int row = r * 64 + srow;
    int ch = sch ^ ((row >> 2) & 3);
    gload16(bptr + (long)row * ldb + k0 + ch * 8,
            lds + buf * TSH + ASH + r * 2048 + t * 8);
  };
  auto stage6 = [&](int buf, int kt) {
    int k0 = kt * 32;
    stageB(buf, k0, 0); stageB(buf, k0, 1);
    stageA(buf, k0, 0); stageA(buf, k0, 1); stageA(buf, k0, 2); stageA(buf, k0, 3);
  };

  // prologue: stage tiles 0,1; wait tile 0 (tile 1's 6 loads stay in flight)
  stage6(0, 0); stage6(1, 1);
  asm volatile("s_waitcnt vmcnt(6)" ::: "memory");
  __builtin_amdgcn_s_barrier();

  for (int kt = 0; kt < NT; ++kt) {
    const char* ab = (const char*)(lds + (kt % 3) * TSH);
    const char* bb = (const char*)(lds + (kt % 3) * TSH + ASH);

    bf16x8 af[8], bf[4];
    #pragma unroll
    for (int m = 0; m < 8; ++m) {
      int row = wr * 128 + m * 16 + c;
      int slot = g ^ ((row >> 2) & 3);    // swizzled ds_read_b128
      af[m] = *reinterpret_cast<const bf16x8*>(ab + row * 64 + slot * 16);
    }
    #pragma unroll
    for (int n = 0; n < 4; ++n) {
      int row = wc * 64 + n * 16 + c;
      int slot = g ^ ((row >> 2) & 3);
      bf[n] = *reinterpret_cast<const bf16x8*>(bb + row * 64 + slot * 16);
    }

    if (kt + 2 < NT) stage6((kt + 2) % 3, kt + 2);

    __builtin_amdgcn_s_barrier();
    asm volatile("s_waitcnt lgkmcnt(0)" ::: "memory");
    __builtin_amdgcn_sched_barrier(0);
    __builtin_amdgcn_s_setprio(1);
    #pragma unroll
    for (int m = 0; m < 8; ++m)
      #pragma unroll
      for (int n = 0; n < 4; ++n)
        acc[m][n] = MFMA(af[m], bf[n], acc[m][n]);
    __builtin_amdgcn_s_setprio(0);
    if (kt < NT - 2)       asm volatile("s_waitcnt vmcnt(6)" ::: "memory");
    else if (kt == NT - 2) asm volatile("s_waitcnt vmcnt(0)" ::: "memory");
    __builtin_amdgcn_s_barrier();
  }

  // ---- epilogue: C/D layout col = lane&15, row = (lane>>4)*4 + j ----
  int rbase = tm * 256 + wr * 128 + g * 4;
  int c0 = tn * 128 + wc * 64 + c;

  if constexpr (EXPSUM) {
    __shared__ float lred[2][256];
    #pragma unroll
    for (int mi = 0; mi < 8; ++mi) {
      #pragma unroll
      for (int j = 0; j < 4; ++j) {
        long ob = (long)b * batchC + (long)(rbase + mi * 16 + j) * ldc + c0;
        float rs = 0.f;
        #pragma unroll
        for (int n = 0; n < 4; ++n) {
          float pv = __expf(acc[mi][n][j] * SCALE);
          ((unsigned short*)Cout)[ob + n * 16] = f2b(pv);
          rs += pv;
        }
        rs += __shfl_xor(rs, 1); rs += __shfl_xor(rs, 2);
        rs += __shfl_xor(rs, 4); rs += __shfl_xor(rs, 8);
        if (c == 0) lred[wc][wr * 128 + mi * 16 + g * 4 + j] = rs;
      }
    }
    __syncthreads();
    {
      int rr = t;                          // 256 threads, 256 rows
      float s = lred[0][rr] + lred[1][rr];
      lpart[((long)b * 2048 + tm * 256 + rr) * 16 + tn] = s;
    }
  } else {
    #pragma unroll
    for (int mi = 0; mi < 8; ++mi) {
      float lv[4];
      if (RS) {
        #pragma unroll
        for (int j = 0; j < 4; ++j)
          lv[j] = rowscale[(long)b * 2048 + rbase + mi * 16 + j];
      }
      #pragma unroll
      for (int n = 0; n < 4; ++n) {
        int col = c0 + n * 16;
        float bv = BIAS ? bias[col] : 0.f;
        long rowb = (long)b * batchC + (long)(rbase + mi * 16) * ldc + col;
        #pragma unroll
        for (int j = 0; j < 4; ++j) {
          float v = acc[mi][n][j] + bv;
          if (RS) v *= lv[j];
          if (BF16OUT) ((unsigned short*)Cout)[rowb + (long)j * ldc] = f2b(v);
          else         ((float*)Cout)[rowb + (long)j * ldc] = v;
        }
      }
    }
  }
}

// ---- 1/rowsum (16 partials per row) ----------------------------------------
__global__ __launch_bounds__(256) void linv_kern(const float* __restrict__ lpart,
                                                 float* __restrict__ linv) {
  int r = blockIdx.x * 256 + threadIdx.x;  // 8192 rows
  float s = 0.f;
  #pragma unroll
  for (int i = 0; i < 16; ++i) s += lpart[(long)r * 16 + i];
  linv[r] = 1.f / s;
}

extern "C" void kernel_launch(void* const* d_in, const int* in_sizes, int n_in,
                              void* d_out, int out_size, void* d_ws, size_t ws_size,
                              hipStream_t stream) {
  (void)in_sizes; (void)n_in; (void)out_size; (void)ws_size;
  const float* x  = (const float*)d_in[0];
  const float* Wq = (const float*)d_in[1];
  const float* bq = (const float*)d_in[2];
  const float* Wk = (const float*)d_in[3];
  const float* bk = (const float*)d_in[4];
  const float* Wv = (const float*)d_in[5];
  const float* bv = (const float*)d_in[6];
  float* out = (float*)d_out;
  char* ws = (char*)d_ws;

  // ws layout (bytes). lpart/linv overlay xb's region: xb is dead after the
  // QKV GEMM, and score/linv run strictly after it (stream-ordered).
  unsigned short* xb   = (unsigned short*)(ws + 0);          // 16,777,216
  float*          lpart= (float*)         (ws + 0);          //    524,288 (overlay)
  float*          linv = (float*)         (ws + 524288);     //     32,768 (overlay)
  unsigned short* wt   = (unsigned short*)(ws + 16777216);   //  3,145,728  [1536][1024]
  float*          bc   = (float*)         (ws + 19922944);   //      6,144
  unsigned short* qkv  = (unsigned short*)(ws + 19929088);   // 25,165,824  [8192][1536]
  unsigned short* vT   = (unsigned short*)(ws + 45094912);   // 16,777,216  [4][1024][2048]
  unsigned short* attn = (unsigned short*)(ws + 61872128);   // 33,554,432  [4][2048][2048]

  convert_x_kern<<<4096, 256, 0, stream>>>(x, xb);
  pack_bias_kern<<<6, 256, 0, stream>>>(bq, bk, bv, bc);
  transpose_w_kern<<<dim3(4, 16), 256, 0, stream>>>(Wq, wt,              256, 1024);
  transpose_w_kern<<<dim3(4, 16), 256, 0, stream>>>(Wk, wt + 256 * 1024, 256, 1024);
  transpose_w_kern<<<dim3(16, 16), 256, 0, stream>>>(Wv, wt + 512 * 1024, 1024, 1024);

  // qkv[8192][1536] = xb[8192][1024] @ wt[1536][1024]^T + bias
  gemm_tb<0, true, true, false, false><<<dim3(384), 256, 0, stream>>>(
      xb, wt, bc, qkv, 32, 1024, 1024, 1536, 0, 0, 0, nullptr, nullptr);

  // vT[b][do][s] = v[b][s][do]
  transpose_v_kern<<<dim3(16, 32, 4), 256, 0, stream>>>(
      qkv + 512, vT, 1536, 2048, (long)2048 * 1536, (long)1024 * 2048);

  // attn[b][q][k] = exp(q.k/16) (unnormalized) + row partial sums
  gemm_tb<2, true, false, false, true><<<dim3(512), 256, 0, stream>>>(
      qkv, qkv + 256, nullptr, attn, 8, 1536, 1536, 2048,
      (long)2048 * 1536, (long)2048 * 1536, (long)2048 * 2048, nullptr, lpart);
  linv_kern<<<32, 256, 0, stream>>>(lpart, linv);

  // out[b][s][do] = (attn[b][s][:] @ vT[b][do][:]^T) * linv[b][s]
  gemm_tb<1, false, false, true, false><<<dim3(256), 256, 0, stream>>>(
      attn, vT, nullptr, out, 64, 2048, 2048, 1024,
      (long)2048 * 2048, (long)1024 * 2048, (long)2048 * 1024, linv, nullptr);
}

// Round 10
// 114.950 us; speedup vs baseline: 1.0865x; 1.0865x over previous
//
#include <hip/hip_runtime.h>
#include <hip/hip_bf16.h>

typedef __attribute__((ext_vector_type(8))) short short8;
typedef __attribute__((ext_vector_type(8))) __bf16 bf16x8;
typedef __attribute__((ext_vector_type(4))) float f32x4;

#define MFMA(a, b, c) __builtin_amdgcn_mfma_f32_16x16x32_bf16((a), (b), (c), 0, 0, 0)
#define SCALE 0.0625f

static __device__ __forceinline__ void gload16(const void* g, void* l) {
  __builtin_amdgcn_global_load_lds(
      (const __attribute__((address_space(1))) void*)g,
      (__attribute__((address_space(3))) void*)l, 16, 0, 0);
}

static __device__ __forceinline__ unsigned short f2b(float f) {
  union { __hip_bfloat16 h; unsigned short u; } cv;
  cv.h = __float2bfloat16(f);
  return cv.u;
}

// ---- x (f32) -> bf16, 8 elems/thread ---------------------------------------
__global__ __launch_bounds__(256) void convert_x_kern(const float* __restrict__ x,
                                                      unsigned short* __restrict__ xb) {
  long i = ((long)blockIdx.x * 256 + threadIdx.x) * 8;
  float4 a = *reinterpret_cast<const float4*>(x + i);
  float4 b = *reinterpret_cast<const float4*>(x + i + 4);
  short8 o;
  o[0] = (short)f2b(a.x); o[1] = (short)f2b(a.y); o[2] = (short)f2b(a.z); o[3] = (short)f2b(a.w);
  o[4] = (short)f2b(b.x); o[5] = (short)f2b(b.y); o[6] = (short)f2b(b.z); o[7] = (short)f2b(b.w);
  *reinterpret_cast<short8*>(xb + i) = o;
}

// ---- pack biases into one [1536] f32 buffer --------------------------------
__global__ void pack_bias_kern(const float* __restrict__ bq, const float* __restrict__ bk,
                               const float* __restrict__ bv, float* __restrict__ bc) {
  int i = blockIdx.x * 256 + threadIdx.x;
  float v = (i < 256) ? bq[i] : (i < 512) ? bk[i - 256] : bv[i - 512];
  bc[i] = v;
}

// ---- transpose f32 [R][C] -> bf16 [C][R], 64x64 tiles ----------------------
__global__ __launch_bounds__(256) void transpose_w_kern(const float* __restrict__ src,
                                                        unsigned short* __restrict__ dst,
                                                        int ldsrc, int lddst) {
  __shared__ __align__(16) unsigned short tile[64][72];
  int r0 = blockIdx.y * 64, c0 = blockIdx.x * 64;
  int t = threadIdx.x;
  #pragma unroll
  for (int it = 0; it < 4; ++it) {
    int idx = it * 1024 + t * 4;
    int row = idx >> 6, col = idx & 63;
    float4 v = *reinterpret_cast<const float4*>(src + (long)(r0 + row) * ldsrc + c0 + col);
    tile[row][col + 0] = f2b(v.x); tile[row][col + 1] = f2b(v.y);
    tile[row][col + 2] = f2b(v.z); tile[row][col + 3] = f2b(v.w);
  }
  __syncthreads();
  #pragma unroll
  for (int it = 0; it < 4; ++it) {
    int idx = it * 1024 + t * 4;
    int orow = idx >> 6, ocol = idx & 63;
    ushort4 o;
    o.x = tile[ocol + 0][orow]; o.y = tile[ocol + 1][orow];
    o.z = tile[ocol + 2][orow]; o.w = tile[ocol + 3][orow];
    *reinterpret_cast<ushort4*>(dst + (long)(c0 + orow) * lddst + r0 + ocol) = o;
  }
}

// ============================================================================
// gemm_pi (QKV + score): BM=256, BN=256, BK=64. 512 thr = 8 waves (2x4),
// wave tile 128x64 (m201 ratio). 2-buffer LDS (128KB), 4 phases/K-tile,
// counted vmcnt (r7-proven, best non-PV aggregate).
// VSPLIT (QKV only): tn>=2 tiles are the V columns -> write vT[b][do][s]
// directly (transposed, packed 8B stores), eliminating transpose_v.
// ============================================================================
template <int SWZ, bool BIAS, bool VSPLIT, bool EXPSUM>
__global__ __launch_bounds__(512, 2) void gemm_pi(
    const unsigned short* __restrict__ A, const unsigned short* __restrict__ B,
    const float* __restrict__ bias, void* __restrict__ Cout,
    int NT, int lda, int ldb, int ldc,
    long batchA, long batchB, long batchC,
    float* __restrict__ lpart,
    unsigned short* __restrict__ vT) {
  constexpr int WM = 128;
  constexpr int ASH = 256 * 64;
  constexpr int TSH = ASH + 256 * 64;
  __shared__ __align__(128) unsigned short lds[2 * TSH];

  int bid = blockIdx.x;
  int b = 0, tm, tn;
  if constexpr (SWZ == 0) {               // QKV: 192 = 8 xcd * (4 tm * 6 tn)
    int xcd = bid & 7, s = bid >> 3;
    tm = xcd * 4 + s / 6; tn = s % 6;
  } else {                                // score: 256 = 8 xcd * 32
    int xcd = bid & 7, s = bid >> 3;
    b = xcd >> 1; tm = (xcd & 1) * 4 + (s >> 3); tn = s & 7;
  }

  int t = threadIdx.x, w = t >> 6, l = t & 63;
  int wr = w >> 2, wc = w & 3;
  int g = l >> 4, c = l & 15;

  f32x4 acc[8][4];
  #pragma unroll
  for (int m = 0; m < 8; ++m)
    #pragma unroll
    for (int n = 0; n < 4; ++n) acc[m][n] = (f32x4){0.f, 0.f, 0.f, 0.f};

  int srow = t >> 3;
  int scb = (t & 7) * 16;
  const unsigned short* aptr = A + (long)b * batchA + (long)(tm * 256) * lda;
  const unsigned short* bptr = B + (long)b * batchB + (long)(tn * 256) * ldb;
  int kb = scb ^ ((srow & 7) << 4);

  auto stageA = [&](int buf, int k0, int r) {
    int row = r * 64 + srow;
    gload16(aptr + (long)row * lda + k0 + (kb >> 1),
            lds + buf * TSH + r * 4096 + t * 8);
  };
  auto stageB = [&](int buf, int k0, int r) {
    int row = r * 64 + srow;
    gload16(bptr + (long)row * ldb + k0 + (kb >> 1),
            lds + buf * TSH + ASH + r * 4096 + t * 8);
  };
  auto ldA = [&](const char* abase, int mh, int kh, int m) {
    int row = wr * WM + mh * 64 + m * 16 + c;
    int pb = row * 128 + (kh * 32 + g * 8) * 2;
    pb ^= ((pb >> 7) & 7) << 4;
    return *reinterpret_cast<const bf16x8*>(abase + pb);
  };
  auto ldB = [&](const char* bbase, int kh, int n) {
    int row = wc * 64 + n * 16 + c;
    int pb = row * 128 + (kh * 32 + g * 8) * 2;
    pb ^= ((pb >> 7) & 7) << 4;
    return *reinterpret_cast<const bf16x8*>(bbase + pb);
  };

  stageB(0, 0, 0); stageB(0, 0, 1); stageB(0, 0, 2); stageB(0, 0, 3);
  stageA(0, 0, 0); stageA(0, 0, 2); stageA(0, 0, 1); stageA(0, 0, 3);
  asm volatile("s_waitcnt vmcnt(0)" ::: "memory");
  __builtin_amdgcn_s_barrier();

  for (int kt = 0; kt < NT; ++kt) {
    int cur = kt & 1, nb = cur ^ 1;
    const char* abase = (const char*)(lds + cur * TSH);
    const char* bbase = (const char*)(lds + cur * TSH + ASH);
    bool more = (kt + 1) < NT;
    int k1 = (kt + 1) * 64;
    bf16x8 bfr[4];
    #pragma unroll
    for (int p = 0; p < 4; ++p) {
      const int kh = p >> 1, mh = p & 1;
      bf16x8 af[4];
      #pragma unroll
      for (int m = 0; m < 4; ++m) af[m] = ldA(abase, mh, kh, m);
      if (mh == 0) {
        #pragma unroll
        for (int n = 0; n < 4; ++n) bfr[n] = ldB(bbase, kh, n);
      }
      if (more) {
        if      (p == 0) { stageB(nb, k1, 0); stageB(nb, k1, 1); }
        else if (p == 1) { stageB(nb, k1, 2); stageB(nb, k1, 3); }
        else if (p == 2) { stageA(nb, k1, 0); stageA(nb, k1, 2); }
        else             { stageA(nb, k1, 1); stageA(nb, k1, 3); }
      }
      __builtin_amdgcn_s_barrier();
      asm volatile("s_waitcnt lgkmcnt(0)" ::: "memory");
      __builtin_amdgcn_sched_barrier(0);
      __builtin_amdgcn_s_setprio(1);
      #pragma unroll
      for (int m = 0; m < 4; ++m)
        #pragma unroll
        for (int n = 0; n < 4; ++n)
          acc[mh * 4 + m][n] = MFMA(af[m], bfr[n], acc[mh * 4 + m][n]);
      __builtin_amdgcn_s_setprio(0);
      if (p == 0) {
        if (kt == NT - 1) asm volatile("s_waitcnt vmcnt(0)" ::: "memory");
        else              asm volatile("s_waitcnt vmcnt(2)" ::: "memory");
      }
      if (p == 3 && more) {
        asm volatile("s_waitcnt vmcnt(2)" ::: "memory");
      }
      __builtin_amdgcn_s_barrier();
    }
  }

  int rbase = tm * 256 + wr * WM + g * 4;
  int c0 = tn * 256 + wc * 64 + c;

  if constexpr (EXPSUM) {
    __shared__ float lred[4][256];
    #pragma unroll
    for (int mi = 0; mi < 8; ++mi) {
      int roff = (mi / 4) * 64 + (mi % 4) * 16;
      #pragma unroll
      for (int j = 0; j < 4; ++j) {
        long ob = (long)b * batchC + (long)(rbase + roff + j) * ldc + c0;
        float rs = 0.f;
        #pragma unroll
        for (int n = 0; n < 4; ++n) {
          float pv = __expf(acc[mi][n][j] * SCALE);
          ((unsigned short*)Cout)[ob + n * 16] = f2b(pv);
          rs += pv;
        }
        rs += __shfl_xor(rs, 1); rs += __shfl_xor(rs, 2);
        rs += __shfl_xor(rs, 4); rs += __shfl_xor(rs, 8);
        if (c == 0) lred[wc][wr * WM + roff + g * 4 + j] = rs;
      }
    }
    __syncthreads();
    for (int rr = t; rr < 256; rr += 512) {
      float s = lred[0][rr] + lred[1][rr] + lred[2][rr] + lred[3][rr];
      lpart[((long)b * 2048 + tm * 256 + rr) * 8 + tn] = s;
    }
  } else if (VSPLIT && tn >= 2) {
    // V region: write vT[b][do][s] directly (transposed). b uniform per block.
    int bb = tm >> 3;
    #pragma unroll
    for (int mi = 0; mi < 8; ++mi) {
      int roff = (mi / 4) * 64 + (mi % 4) * 16;
      int s0 = (rbase + roff) & 2047;
      #pragma unroll
      for (int n = 0; n < 4; ++n) {
        int col = c0 + n * 16;
        float bv = BIAS ? bias[col] : 0.f;
        ushort4 pk;
        pk.x = f2b(acc[mi][n][0] + bv); pk.y = f2b(acc[mi][n][1] + bv);
        pk.z = f2b(acc[mi][n][2] + bv); pk.w = f2b(acc[mi][n][3] + bv);
        *reinterpret_cast<ushort4*>(vT + (long)bb * 2097152 +
                                    (long)(col - 512) * 2048 + s0) = pk;
      }
    }
  } else {
    #pragma unroll
    for (int mi = 0; mi < 8; ++mi) {
      int roff = (mi / 4) * 64 + (mi % 4) * 16;
      #pragma unroll
      for (int n = 0; n < 4; ++n) {
        int col = c0 + n * 16;
        float bv = BIAS ? bias[col] : 0.f;
        long rowb = (long)b * batchC + (long)(rbase + roff) * ldc + col;
        #pragma unroll
        for (int j = 0; j < 4; ++j)
          ((unsigned short*)Cout)[rowb + (long)j * ldc] = f2b(acc[mi][n][j] + bv);
      }
    }
  }
}

// ============================================================================
// gemm_pv (PV): r4's proven 1-barrier/K-tile schedule (44.7us) + r6's proven
// batch->XCD-pair affinity map (FETCH 82->33MB). BM=128, BN=256, BK=64,
// 512 thr = 8 waves (2x4), wave 64x64, 3-buffer LDS, stage t+2, vmcnt(6).
// ============================================================================
__global__ __launch_bounds__(512, 2) void gemm_pv(
    const unsigned short* __restrict__ A,   // attn [4][2048][2048] bf16
    const unsigned short* __restrict__ B,   // vT   [4][1024][2048] bf16
    float* __restrict__ Cout,               // out  [4][2048][1024] f32
    const float* __restrict__ linv) {
  constexpr int NT = 32;
  constexpr int ASH = 128 * 64;             // 16KB
  constexpr int TSH = ASH + 256 * 64;       // 48KB
  __shared__ __align__(128) unsigned short lds[3 * TSH];

  int bid = blockIdx.x;                     // 256 = 8 xcd * 32
  int xcd = bid & 7, sidx = bid >> 3;
  int b = xcd >> 1;
  int tm = (xcd & 1) * 8 + (sidx >> 2), tn = sidx & 3;

  int t = threadIdx.x, w = t >> 6, l = t & 63;
  int wr = w >> 2, wc = w & 3;
  int g = l >> 4, c = l & 15;

  f32x4 acc[4][4];
  #pragma unroll
  for (int m = 0; m < 4; ++m)
    #pragma unroll
    for (int n = 0; n < 4; ++n) acc[m][n] = (f32x4){0.f, 0.f, 0.f, 0.f};

  int srow = t >> 3;
  int scb = (t & 7) * 16;
  int kb = scb ^ ((srow & 7) << 4);
  const unsigned short* aptr = A + (long)b * 4194304 + (long)(tm * 128) * 2048;
  const unsigned short* bptr = B + (long)b * 2097152 + (long)(tn * 256) * 2048;

  auto stageA = [&](int buf, int k0) {
    #pragma unroll
    for (int r = 0; r < 2; ++r) {
      int row = r * 64 + srow;
      gload16(aptr + (long)row * 2048 + k0 + (kb >> 1),
              lds + buf * TSH + r * 4096 + t * 8);
    }
  };
  auto stageB = [&](int buf, int k0) {
    #pragma unroll
    for (int r = 0; r < 4; ++r) {
      int row = r * 64 + srow;
      gload16(bptr + (long)row * 2048 + k0 + (kb >> 1),
              lds + buf * TSH + ASH + r * 4096 + t * 8);
    }
  };

  stageA(0, 0); stageB(0, 0);
  stageA(1, 64); stageB(1, 64);
  asm volatile("s_waitcnt vmcnt(6)" ::: "memory");
  __builtin_amdgcn_s_barrier();

  for (int kt = 0; kt < NT; ++kt) {
    int cur = kt % 3, nxt = (kt + 2) % 3;
    const char* abase = (const char*)(lds + cur * TSH);
    const char* bbase = abase + ASH * 2;

    bf16x8 af[2][4], bf[2][4];
    #pragma unroll
    for (int sk = 0; sk < 2; ++sk) {
      #pragma unroll
      for (int m = 0; m < 4; ++m) {
        int p = (wr * 64 + m * 16 + c) * 128 + (sk * 32 + g * 8) * 2;
        p ^= ((p >> 7) & 7) << 4;
        af[sk][m] = *reinterpret_cast<const bf16x8*>(abase + p);
      }
      #pragma unroll
      for (int n = 0; n < 4; ++n) {
        int p = (wc * 64 + n * 16 + c) * 128 + (sk * 32 + g * 8) * 2;
        p ^= ((p >> 7) & 7) << 4;
        bf[sk][n] = *reinterpret_cast<const bf16x8*>(bbase + p);
      }
    }

    if (kt + 2 < NT) {
      int k2 = (kt + 2) * 64;
      stageA(nxt, k2); stageB(nxt, k2);
    }

    __builtin_amdgcn_s_setprio(1);
    #pragma unroll
    for (int sk = 0; sk < 2; ++sk)
      #pragma unroll
      for (int m = 0; m < 4; ++m)
        #pragma unroll
        for (int n = 0; n < 4; ++n)
          acc[m][n] = MFMA(af[sk][m], bf[sk][n], acc[m][n]);
    __builtin_amdgcn_s_setprio(0);

    if (kt < NT - 1) {
      if (kt == NT - 2) asm volatile("s_waitcnt vmcnt(0)" ::: "memory");
      else              asm volatile("s_waitcnt vmcnt(6)" ::: "memory");
      __builtin_amdgcn_s_barrier();
    }
  }

  int rbase = tm * 128 + wr * 64 + g * 4;
  int c0 = tn * 256 + wc * 64 + c;
  #pragma unroll
  for (int mi = 0; mi < 4; ++mi) {
    float lv[4];
    #pragma unroll
    for (int j = 0; j < 4; ++j)
      lv[j] = linv[(long)b * 2048 + rbase + mi * 16 + j];
    #pragma unroll
    for (int n = 0; n < 4; ++n) {
      long rowb = (long)b * 2097152 + (long)(rbase + mi * 16) * 1024 + c0 + n * 16;
      #pragma unroll
      for (int j = 0; j < 4; ++j)
        Cout[rowb + (long)j * 1024] = acc[mi][n][j] * lv[j];
    }
  }
}

// ---- 1/rowsum (8 partials per row) -----------------------------------------
__global__ __launch_bounds__(256) void linv_kern(const float* __restrict__ lpart,
                                                 float* __restrict__ linv) {
  int r = blockIdx.x * 256 + threadIdx.x;  // 8192 rows
  float s = 0.f;
  #pragma unroll
  for (int i = 0; i < 8; ++i) s += lpart[(long)r * 8 + i];
  linv[r] = 1.f / s;
}

extern "C" void kernel_launch(void* const* d_in, const int* in_sizes, int n_in,
                              void* d_out, int out_size, void* d_ws, size_t ws_size,
                              hipStream_t stream) {
  (void)in_sizes; (void)n_in; (void)out_size; (void)ws_size;
  const float* x  = (const float*)d_in[0];
  const float* Wq = (const float*)d_in[1];
  const float* bq = (const float*)d_in[2];
  const float* Wk = (const float*)d_in[3];
  const float* bk = (const float*)d_in[4];
  const float* Wv = (const float*)d_in[5];
  const float* bv = (const float*)d_in[6];
  float* out = (float*)d_out;
  char* ws = (char*)d_ws;

  // ws layout (bytes). lpart/linv overlay xb's region: xb is dead after the
  // QKV GEMM, and score/linv run strictly after it (stream-ordered).
  unsigned short* xb   = (unsigned short*)(ws + 0);          // 16,777,216
  float*          lpart= (float*)         (ws + 0);          //    262,144 (overlay)
  float*          linv = (float*)         (ws + 262144);     //     32,768 (overlay)
  unsigned short* wt   = (unsigned short*)(ws + 16777216);   //  3,145,728  [1536][1024]
  float*          bc   = (float*)         (ws + 19922944);   //      6,144
  unsigned short* qkv  = (unsigned short*)(ws + 19929088);   // 25,165,824  [8192][1536]
  unsigned short* vT   = (unsigned short*)(ws + 45094912);   // 16,777,216  [4][1024][2048]
  unsigned short* attn = (unsigned short*)(ws + 61872128);   // 33,554,432  [4][2048][2048]

  convert_x_kern<<<4096, 256, 0, stream>>>(x, xb);
  pack_bias_kern<<<6, 256, 0, stream>>>(bq, bk, bv, bc);
  transpose_w_kern<<<dim3(4, 16), 256, 0, stream>>>(Wq, wt,              256, 1024);
  transpose_w_kern<<<dim3(4, 16), 256, 0, stream>>>(Wk, wt + 256 * 1024, 256, 1024);
  transpose_w_kern<<<dim3(16, 16), 256, 0, stream>>>(Wv, wt + 512 * 1024, 1024, 1024);

  // qkv[8192][1536] = xb @ wt^T + bias; V columns stream directly to vT
  gemm_pi<0, true, true, false><<<dim3(192), 512, 0, stream>>>(
      xb, wt, bc, qkv, 16, 1024, 1024, 1536, 0, 0, 0, nullptr, vT);

  // attn[b][q][k] = exp(q.k/16) (unnormalized) + row partial sums
  gemm_pi<1, false, false, true><<<dim3(256), 512, 0, stream>>>(
      qkv, qkv + 256, nullptr, attn, 4, 1536, 1536, 2048,
      (long)2048 * 1536, (long)2048 * 1536, (long)2048 * 2048, lpart, nullptr);
  linv_kern<<<32, 256, 0, stream>>>(lpart, linv);

  // out[b][s][do] = (attn[b][s][:] @ vT[b][do][:]^T) * linv[b][s]
  gemm_pv<<<dim3(256), 512, 0, stream>>>(attn, vT, out, linv);
}

// Round 11
// 109.510 us; speedup vs baseline: 1.1405x; 1.0497x over previous
//
#include <hip/hip_runtime.h>
#include <hip/hip_bf16.h>

typedef __attribute__((ext_vector_type(8))) short short8;
typedef __attribute__((ext_vector_type(8))) __bf16 bf16x8;
typedef __attribute__((ext_vector_type(4))) float f32x4;

#define MFMA(a, b, c) __builtin_amdgcn_mfma_f32_16x16x32_bf16((a), (b), (c), 0, 0, 0)
#define SCALE 0.0625f

static __device__ __forceinline__ void gload16(const void* g, void* l) {
  __builtin_amdgcn_global_load_lds(
      (const __attribute__((address_space(1))) void*)g,
      (__attribute__((address_space(3))) void*)l, 16, 0, 0);
}

static __device__ __forceinline__ unsigned short f2b(float f) {
  union { __hip_bfloat16 h; unsigned short u; } cv;
  cv.h = __float2bfloat16(f);
  return cv.u;
}

// ---- x (f32) -> bf16, 8 elems/thread ---------------------------------------
__global__ __launch_bounds__(256) void convert_x_kern(const float* __restrict__ x,
                                                      unsigned short* __restrict__ xb) {
  long i = ((long)blockIdx.x * 256 + threadIdx.x) * 8;
  float4 a = *reinterpret_cast<const float4*>(x + i);
  float4 b = *reinterpret_cast<const float4*>(x + i + 4);
  short8 o;
  o[0] = (short)f2b(a.x); o[1] = (short)f2b(a.y); o[2] = (short)f2b(a.z); o[3] = (short)f2b(a.w);
  o[4] = (short)f2b(b.x); o[5] = (short)f2b(b.y); o[6] = (short)f2b(b.z); o[7] = (short)f2b(b.w);
  *reinterpret_cast<short8*>(xb + i) = o;
}

// ---- pack biases into one [1536] f32 buffer --------------------------------
__global__ void pack_bias_kern(const float* __restrict__ bq, const float* __restrict__ bk,
                               const float* __restrict__ bv, float* __restrict__ bc) {
  int i = blockIdx.x * 256 + threadIdx.x;
  float v = (i < 256) ? bq[i] : (i < 512) ? bk[i - 256] : bv[i - 512];
  bc[i] = v;
}

// ---- transpose f32 [R][C] -> bf16 [C][R], 64x64 tiles ----------------------
__global__ __launch_bounds__(256) void transpose_w_kern(const float* __restrict__ src,
                                                        unsigned short* __restrict__ dst,
                                                        int ldsrc, int lddst) {
  __shared__ __align__(16) unsigned short tile[64][72];
  int r0 = blockIdx.y * 64, c0 = blockIdx.x * 64;
  int t = threadIdx.x;
  #pragma unroll
  for (int it = 0; it < 4; ++it) {
    int idx = it * 1024 + t * 4;
    int row = idx >> 6, col = idx & 63;
    float4 v = *reinterpret_cast<const float4*>(src + (long)(r0 + row) * ldsrc + c0 + col);
    tile[row][col + 0] = f2b(v.x); tile[row][col + 1] = f2b(v.y);
    tile[row][col + 2] = f2b(v.z); tile[row][col + 3] = f2b(v.w);
  }
  __syncthreads();
  #pragma unroll
  for (int it = 0; it < 4; ++it) {
    int idx = it * 1024 + t * 4;
    int orow = idx >> 6, ocol = idx & 63;
    ushort4 o;
    o.x = tile[ocol + 0][orow]; o.y = tile[ocol + 1][orow];
    o.z = tile[ocol + 2][orow]; o.w = tile[ocol + 3][orow];
    *reinterpret_cast<ushort4*>(dst + (long)(c0 + orow) * lddst + r0 + ocol) = o;
  }
}

// ============================================================================
// gemm_pi (QKV + score): BM=256, BN in {192,256}, BK=64. 512 thr = 8 waves
// (2M x 4N), wave tile 128 x BN/4. 2-buffer LDS, 4 phases/K-tile, counted
// vmcnt, setprio.
// BN=192 (QKV): grid 32x8 = 256 blocks = exactly 1/CU (fixes the 25%-idle
//   loss of the 192-block BN=256 config). 7 loads/thread/tile; stage plan
//   p0:{B0,B1,B2} p1:{A0,A2} p2:{A1,A3}; tile-end vmcnt(2) retires
//   B*3+A0+A2 (needed at t+1 p0), p0-end vmcnt(3) retires A1,A3 (p1).
// BN=256 (score): r7/r10-proven 8-load plan, vmcnt(2)/vmcnt(2).
// VSPLIT (QKV only): cols >= 512 are V -> write vT[b][do][s] directly.
// ============================================================================
template <int SWZ, int BN, bool BIAS, bool VSPLIT, bool EXPSUM>
__global__ __launch_bounds__(512, 2) void gemm_pi(
    const unsigned short* __restrict__ A, const unsigned short* __restrict__ B,
    const float* __restrict__ bias, void* __restrict__ Cout,
    int NT, int lda, int ldb, int ldc,
    long batchA, long batchB, long batchC,
    float* __restrict__ lpart,
    unsigned short* __restrict__ vT) {
  constexpr int WM = 128;
  constexpr int WN = BN / 4;              // wave cols (48 or 64)
  constexpr int NF = BN / 64;             // N frags per wave (3 or 4)
  constexpr int BR = BN / 64;             // B staging rounds (3 or 4)
  constexpr int ASH = 256 * 64;
  constexpr int TSH = ASH + BN * 64;
  __shared__ __align__(128) unsigned short lds[2 * TSH];

  int bid = blockIdx.x;
  int b = 0, tm, tn;
  if constexpr (SWZ == 0) {               // QKV: 256 = 8 xcd * (4 tm * 8 tn)
    int xcd = bid & 7, s = bid >> 3;
    tm = xcd * 4 + (s >> 3); tn = s & 7;
  } else {                                // score: 256 = 8 xcd * 32
    int xcd = bid & 7, s = bid >> 3;
    b = xcd >> 1; tm = (xcd & 1) * 4 + (s >> 3); tn = s & 7;
  }

  int t = threadIdx.x, w = t >> 6, l = t & 63;
  int wr = w >> 2, wc = w & 3;
  int g = l >> 4, c = l & 15;

  f32x4 acc[8][NF];
  #pragma unroll
  for (int m = 0; m < 8; ++m)
    #pragma unroll
    for (int n = 0; n < NF; ++n) acc[m][n] = (f32x4){0.f, 0.f, 0.f, 0.f};

  int srow = t >> 3;
  int scb = (t & 7) * 16;
  const unsigned short* aptr = A + (long)b * batchA + (long)(tm * 256) * lda;
  const unsigned short* bptr = B + (long)b * batchB + (long)(tn * BN) * ldb;
  int kb = scb ^ ((srow & 7) << 4);

  auto stageA = [&](int buf, int k0, int r) {
    int row = r * 64 + srow;
    gload16(aptr + (long)row * lda + k0 + (kb >> 1),
            lds + buf * TSH + r * 4096 + t * 8);
  };
  auto stageB = [&](int buf, int k0, int r) {
    int row = r * 64 + srow;
    gload16(bptr + (long)row * ldb + k0 + (kb >> 1),
            lds + buf * TSH + ASH + r * 4096 + t * 8);
  };
  auto ldA = [&](const char* abase, int mh, int kh, int m) {
    int row = wr * WM + mh * 64 + m * 16 + c;
    int pb = row * 128 + (kh * 32 + g * 8) * 2;
    pb ^= ((pb >> 7) & 7) << 4;
    return *reinterpret_cast<const bf16x8*>(abase + pb);
  };
  auto ldB = [&](const char* bbase, int kh, int n) {
    int row = wc * WN + n * 16 + c;
    int pb = row * 128 + (kh * 32 + g * 8) * 2;
    pb ^= ((pb >> 7) & 7) << 4;
    return *reinterpret_cast<const bf16x8*>(bbase + pb);
  };

  // prologue: stage tile 0 fully, drain, barrier
  #pragma unroll
  for (int r = 0; r < BR; ++r) stageB(0, 0, r);
  stageA(0, 0, 0); stageA(0, 0, 2); stageA(0, 0, 1); stageA(0, 0, 3);
  asm volatile("s_waitcnt vmcnt(0)" ::: "memory");
  __builtin_amdgcn_s_barrier();

  for (int kt = 0; kt < NT; ++kt) {
    int cur = kt & 1, nb = cur ^ 1;
    const char* abase = (const char*)(lds + cur * TSH);
    const char* bbase = (const char*)(lds + cur * TSH + ASH);
    bool more = (kt + 1) < NT;
    int k1 = (kt + 1) * 64;
    bf16x8 bfr[NF];
    #pragma unroll
    for (int p = 0; p < 4; ++p) {
      const int kh = p >> 1, mh = p & 1;
      bf16x8 af[4];
      #pragma unroll
      for (int m = 0; m < 4; ++m) af[m] = ldA(abase, mh, kh, m);
      if (mh == 0) {
        #pragma unroll
        for (int n = 0; n < NF; ++n) bfr[n] = ldB(bbase, kh, n);
      }
      if (more) {
        if constexpr (BN == 256) {
          if      (p == 0) { stageB(nb, k1, 0); stageB(nb, k1, 1); }
          else if (p == 1) { stageB(nb, k1, 2); stageB(nb, k1, 3); }
          else if (p == 2) { stageA(nb, k1, 0); stageA(nb, k1, 2); }
          else             { stageA(nb, k1, 1); stageA(nb, k1, 3); }
        } else {
          if      (p == 0) { stageB(nb, k1, 0); stageB(nb, k1, 1); stageB(nb, k1, 2); }
          else if (p == 1) { stageA(nb, k1, 0); stageA(nb, k1, 2); }
          else if (p == 2) { stageA(nb, k1, 1); stageA(nb, k1, 3); }
        }
      }
      __builtin_amdgcn_s_barrier();
      asm volatile("s_waitcnt lgkmcnt(0)" ::: "memory");
      __builtin_amdgcn_sched_barrier(0);
      __builtin_amdgcn_s_setprio(1);
      #pragma unroll
      for (int m = 0; m < 4; ++m)
        #pragma unroll
        for (int n = 0; n < NF; ++n)
          acc[mh * 4 + m][n] = MFMA(af[m], bfr[n], acc[mh * 4 + m][n]);
      __builtin_amdgcn_s_setprio(0);
      if (p == 0) {                       // retire this tile's A1,A3
        if (kt == NT - 1) asm volatile("s_waitcnt vmcnt(0)" ::: "memory");
        else if (BN == 256) asm volatile("s_waitcnt vmcnt(2)" ::: "memory");
        else                asm volatile("s_waitcnt vmcnt(3)" ::: "memory");
      }
      if (p == 3 && more) {               // retire next tile's B rounds + A0,A2
        asm volatile("s_waitcnt vmcnt(2)" ::: "memory");
      }
      __builtin_amdgcn_s_barrier();
    }
  }

  int rbase = tm * 256 + wr * WM + g * 4;
  int c0 = tn * BN + wc * WN + c;

  if constexpr (EXPSUM) {
    __shared__ float lred[4][256];
    #pragma unroll
    for (int mi = 0; mi < 8; ++mi) {
      int roff = (mi / 4) * 64 + (mi % 4) * 16;
      #pragma unroll
      for (int j = 0; j < 4; ++j) {
        long ob = (long)b * batchC + (long)(rbase + roff + j) * ldc + c0;
        float rs = 0.f;
        #pragma unroll
        for (int n = 0; n < NF; ++n) {
          float pv = __expf(acc[mi][n][j] * SCALE);
          ((unsigned short*)Cout)[ob + n * 16] = f2b(pv);
          rs += pv;
        }
        rs += __shfl_xor(rs, 1); rs += __shfl_xor(rs, 2);
        rs += __shfl_xor(rs, 4); rs += __shfl_xor(rs, 8);
        if (c == 0) lred[wc][wr * WM + roff + g * 4 + j] = rs;
      }
    }
    __syncthreads();
    for (int rr = t; rr < 256; rr += 512) {
      float s = lred[0][rr] + lred[1][rr] + lred[2][rr] + lred[3][rr];
      lpart[((long)b * 2048 + tm * 256 + rr) * 8 + tn] = s;
    }
  } else {
    #pragma unroll
    for (int mi = 0; mi < 8; ++mi) {
      int roff = (mi / 4) * 64 + (mi % 4) * 16;
      int s0 = (rbase + roff) & 2047;
      #pragma unroll
      for (int n = 0; n < NF; ++n) {
        int col = c0 + n * 16;
        float bv = BIAS ? bias[col] : 0.f;
        if (VSPLIT && (col - c) >= 512) {
          // V region: write vT[b][do][s] directly (transposed, 8B stores)
          int bb = tm >> 3;
          ushort4 pk;
          pk.x = f2b(acc[mi][n][0] + bv); pk.y = f2b(acc[mi][n][1] + bv);
          pk.z = f2b(acc[mi][n][2] + bv); pk.w = f2b(acc[mi][n][3] + bv);
          *reinterpret_cast<ushort4*>(vT + (long)bb * 2097152 +
                                      (long)(col - 512) * 2048 + s0) = pk;
        } else {
          long rowb = (long)b * batchC + (long)(rbase + roff) * ldc + col;
          #pragma unroll
          for (int j = 0; j < 4; ++j)
            ((unsigned short*)Cout)[rowb + (long)j * ldc] = f2b(acc[mi][n][j] + bv);
        }
      }
    }
  }
}

// ============================================================================
// gemm_pv (PV): r4-proven 1-barrier/K-tile schedule + batch->XCD-pair map.
// BM=128, BN=256, BK=64, 512 thr, wave 64x64, 3-buffer LDS, vmcnt(6).
// ============================================================================
__global__ __launch_bounds__(512, 2) void gemm_pv(
    const unsigned short* __restrict__ A,   // attn [4][2048][2048] bf16
    const unsigned short* __restrict__ B,   // vT   [4][1024][2048] bf16
    float* __restrict__ Cout,               // out  [4][2048][1024] f32
    const float* __restrict__ linv) {
  constexpr int NT = 32;
  constexpr int ASH = 128 * 64;
  constexpr int TSH = ASH + 256 * 64;
  __shared__ __align__(128) unsigned short lds[3 * TSH];

  int bid = blockIdx.x;                     // 256 = 8 xcd * 32
  int xcd = bid & 7, sidx = bid >> 3;
  int b = xcd >> 1;
  int tm = (xcd & 1) * 8 + (sidx >> 2), tn = sidx & 3;

  int t = threadIdx.x, w = t >> 6, l = t & 63;
  int wr = w >> 2, wc = w & 3;
  int g = l >> 4, c = l & 15;

  f32x4 acc[4][4];
  #pragma unroll
  for (int m = 0; m < 4; ++m)
    #pragma unroll
    for (int n = 0; n < 4; ++n) acc[m][n] = (f32x4){0.f, 0.f, 0.f, 0.f};

  int srow = t >> 3;
  int scb = (t & 7) * 16;
  int kb = scb ^ ((srow & 7) << 4);
  const unsigned short* aptr = A + (long)b * 4194304 + (long)(tm * 128) * 2048;
  const unsigned short* bptr = B + (long)b * 2097152 + (long)(tn * 256) * 2048;

  auto stageA = [&](int buf, int k0) {
    #pragma unroll
    for (int r = 0; r < 2; ++r) {
      int row = r * 64 + srow;
      gload16(aptr + (long)row * 2048 + k0 + (kb >> 1),
              lds + buf * TSH + r * 4096 + t * 8);
    }
  };
  auto stageB = [&](int buf, int k0) {
    #pragma unroll
    for (int r = 0; r < 4; ++r) {
      int row = r * 64 + srow;
      gload16(bptr + (long)row * 2048 + k0 + (kb >> 1),
              lds + buf * TSH + ASH + r * 4096 + t * 8);
    }
  };

  stageA(0, 0); stageB(0, 0);
  stageA(1, 64); stageB(1, 64);
  asm volatile("s_waitcnt vmcnt(6)" ::: "memory");
  __builtin_amdgcn_s_barrier();

  for (int kt = 0; kt < NT; ++kt) {
    int cur = kt % 3, nxt = (kt + 2) % 3;
    const char* abase = (const char*)(lds + cur * TSH);
    const char* bbase = abase + ASH * 2;

    bf16x8 af[2][4], bf[2][4];
    #pragma unroll
    for (int sk = 0; sk < 2; ++sk) {
      #pragma unroll
      for (int m = 0; m < 4; ++m) {
        int p = (wr * 64 + m * 16 + c) * 128 + (sk * 32 + g * 8) * 2;
        p ^= ((p >> 7) & 7) << 4;
        af[sk][m] = *reinterpret_cast<const bf16x8*>(abase + p);
      }
      #pragma unroll
      for (int n = 0; n < 4; ++n) {
        int p = (wc * 64 + n * 16 + c) * 128 + (sk * 32 + g * 8) * 2;
        p ^= ((p >> 7) & 7) << 4;
        bf[sk][n] = *reinterpret_cast<const bf16x8*>(bbase + p);
      }
    }

    if (kt + 2 < NT) {
      int k2 = (kt + 2) * 64;
      stageA(nxt, k2); stageB(nxt, k2);
    }

    __builtin_amdgcn_s_setprio(1);
    #pragma unroll
    for (int sk = 0; sk < 2; ++sk)
      #pragma unroll
      for (int m = 0; m < 4; ++m)
        #pragma unroll
        for (int n = 0; n < 4; ++n)
          acc[m][n] = MFMA(af[sk][m], bf[sk][n], acc[m][n]);
    __builtin_amdgcn_s_setprio(0);

    if (kt < NT - 1) {
      if (kt == NT - 2) asm volatile("s_waitcnt vmcnt(0)" ::: "memory");
      else              asm volatile("s_waitcnt vmcnt(6)" ::: "memory");
      __builtin_amdgcn_s_barrier();
    }
  }

  int rbase = tm * 128 + wr * 64 + g * 4;
  int c0 = tn * 256 + wc * 64 + c;
  #pragma unroll
  for (int mi = 0; mi < 4; ++mi) {
    float lv[4];
    #pragma unroll
    for (int j = 0; j < 4; ++j)
      lv[j] = linv[(long)b * 2048 + rbase + mi * 16 + j];
    #pragma unroll
    for (int n = 0; n < 4; ++n) {
      long rowb = (long)b * 2097152 + (long)(rbase + mi * 16) * 1024 + c0 + n * 16;
      #pragma unroll
      for (int j = 0; j < 4; ++j)
        Cout[rowb + (long)j * 1024] = acc[mi][n][j] * lv[j];
    }
  }
}

// ---- 1/rowsum (8 partials per row) -----------------------------------------
__global__ __launch_bounds__(256) void linv_kern(const float* __restrict__ lpart,
                                                 float* __restrict__ linv) {
  int r = blockIdx.x * 256 + threadIdx.x;  // 8192 rows
  float s = 0.f;
  #pragma unroll
  for (int i = 0; i < 8; ++i) s += lpart[(long)r * 8 + i];
  linv[r] = 1.f / s;
}

extern "C" void kernel_launch(void* const* d_in, const int* in_sizes, int n_in,
                              void* d_out, int out_size, void* d_ws, size_t ws_size,
                              hipStream_t stream) {
  (void)in_sizes; (void)n_in; (void)out_size; (void)ws_size;
  const float* x  = (const float*)d_in[0];
  const float* Wq = (const float*)d_in[1];
  const float* bq = (const float*)d_in[2];
  const float* Wk = (const float*)d_in[3];
  const float* bk = (const float*)d_in[4];
  const float* Wv = (const float*)d_in[5];
  const float* bv = (const float*)d_in[6];
  float* out = (float*)d_out;
  char* ws = (char*)d_ws;

  // ws layout (bytes). lpart/linv overlay xb's region: xb is dead after the
  // QKV GEMM, and score/linv run strictly after it (stream-ordered).
  unsigned short* xb   = (unsigned short*)(ws + 0);          // 16,777,216
  float*          lpart= (float*)         (ws + 0);          //    262,144 (overlay)
  float*          linv = (float*)         (ws + 262144);     //     32,768 (overlay)
  unsigned short* wt   = (unsigned short*)(ws + 16777216);   //  3,145,728  [1536][1024]
  float*          bc   = (float*)         (ws + 19922944);   //      6,144
  unsigned short* qkv  = (unsigned short*)(ws + 19929088);   // 25,165,824  [8192][1536]
  unsigned short* vT   = (unsigned short*)(ws + 45094912);   // 16,777,216  [4][1024][2048]
  unsigned short* attn = (unsigned short*)(ws + 61872128);   // 33,554,432  [4][2048][2048]

  convert_x_kern<<<4096, 256, 0, stream>>>(x, xb);
  pack_bias_kern<<<6, 256, 0, stream>>>(bq, bk, bv, bc);
  transpose_w_kern<<<dim3(4, 16), 256, 0, stream>>>(Wq, wt,              256, 1024);
  transpose_w_kern<<<dim3(4, 16), 256, 0, stream>>>(Wk, wt + 256 * 1024, 256, 1024);
  transpose_w_kern<<<dim3(16, 16), 256, 0, stream>>>(Wv, wt + 512 * 1024, 1024, 1024);

  // qkv[8192][1536] = xb @ wt^T + bias; V columns stream directly to vT
  // BN=192 -> grid 32x8 = 256 blocks = 1 per CU
  gemm_pi<0, 192, true, true, false><<<dim3(256), 512, 0, stream>>>(
      xb, wt, bc, qkv, 16, 1024, 1024, 1536, 0, 0, 0, nullptr, vT);

  // attn[b][q][k] = exp(q.k/16) (unnormalized) + row partial sums
  gemm_pi<1, 256, false, false, true><<<dim3(256), 512, 0, stream>>>(
      qkv, qkv + 256, nullptr, attn, 4, 1536, 1536, 2048,
      (long)2048 * 1536, (long)2048 * 1536, (long)2048 * 2048, lpart, nullptr);
  linv_kern<<<32, 256, 0, stream>>>(lpart, linv);

  // out[b][s][do] = (attn[b][s][:] @ vT[b][do][:]^T) * linv[b][s]
  gemm_pv<<<dim3(256), 512, 0, stream>>>(attn, vT, out, linv);
}

// Round 12
// 101.515 us; speedup vs baseline: 1.2303x; 1.0788x over previous
//
#include <hip/hip_runtime.h>
#include <hip/hip_bf16.h>

typedef __attribute__((ext_vector_type(8))) short short8;
typedef __attribute__((ext_vector_type(8))) __bf16 bf16x8;
typedef __attribute__((ext_vector_type(4))) float f32x4;

#define MFMA(a, b, c) __builtin_amdgcn_mfma_f32_16x16x32_bf16((a), (b), (c), 0, 0, 0)
#define SCALE 0.0625f

static __device__ __forceinline__ void gload16(const void* g, void* l) {
  __builtin_amdgcn_global_load_lds(
      (const __attribute__((address_space(1))) void*)g,
      (__attribute__((address_space(3))) void*)l, 16, 0, 0);
}

static __device__ __forceinline__ unsigned short f2b(float f) {
  union { __hip_bfloat16 h; unsigned short u; } cv;
  cv.h = __float2bfloat16(f);
  return cv.u;
}

// ---- fused prep: convert_x + pack_bias + transpose_w(Wq,Wk,Wv) -------------
// blocks 0..4095: x f32 -> bf16 (8 elems/thread)
// blocks 4096..4101: bias pack
// blocks 4102..4165: Wq^T, 4166..4229: Wk^T, 4230..4485: Wv^T
__global__ __launch_bounds__(256) void prep_kern(
    const float* __restrict__ x, unsigned short* __restrict__ xb,
    const float* __restrict__ bq, const float* __restrict__ bk,
    const float* __restrict__ bv, float* __restrict__ bc,
    const float* __restrict__ Wq, const float* __restrict__ Wk,
    const float* __restrict__ Wv, unsigned short* __restrict__ wt) {
  __shared__ __align__(16) unsigned short tile[64][72];
  int bid = blockIdx.x, t = threadIdx.x;
  if (bid < 4096) {
    long i = ((long)bid * 256 + t) * 8;
    float4 a = *reinterpret_cast<const float4*>(x + i);
    float4 b = *reinterpret_cast<const float4*>(x + i + 4);
    short8 o;
    o[0] = (short)f2b(a.x); o[1] = (short)f2b(a.y); o[2] = (short)f2b(a.z); o[3] = (short)f2b(a.w);
    o[4] = (short)f2b(b.x); o[5] = (short)f2b(b.y); o[6] = (short)f2b(b.z); o[7] = (short)f2b(b.w);
    *reinterpret_cast<short8*>(xb + i) = o;
    return;
  }
  if (bid < 4102) {
    int i = (bid - 4096) * 256 + t;
    float v = (i < 256) ? bq[i] : (i < 512) ? bk[i - 256] : bv[i - 512];
    bc[i] = v;
    return;
  }
  const float* src; unsigned short* dst; int ldsrc, lam;
  if (bid < 4166)      { lam = bid - 4102; src = Wq; dst = wt;              ldsrc = 256;
                         lam = (lam & 3) | ((lam >> 2) << 8); }
  else if (bid < 4230) { lam = bid - 4166; src = Wk; dst = wt + 256 * 1024; ldsrc = 256;
                         lam = (lam & 3) | ((lam >> 2) << 8); }
  else                 { lam = bid - 4230; src = Wv; dst = wt + 512 * 1024; ldsrc = 1024;
                         lam = (lam & 15) | ((lam >> 4) << 8); }
  int c0 = (lam & 255) * 64, r0 = (lam >> 8) * 64;
  #pragma unroll
  for (int it = 0; it < 4; ++it) {
    int idx = it * 1024 + t * 4;
    int row = idx >> 6, col = idx & 63;
    float4 v = *reinterpret_cast<const float4*>(src + (long)(r0 + row) * ldsrc + c0 + col);
    tile[row][col + 0] = f2b(v.x); tile[row][col + 1] = f2b(v.y);
    tile[row][col + 2] = f2b(v.z); tile[row][col + 3] = f2b(v.w);
  }
  __syncthreads();
  #pragma unroll
  for (int it = 0; it < 4; ++it) {
    int idx = it * 1024 + t * 4;
    int orow = idx >> 6, ocol = idx & 63;
    ushort4 o;
    o.x = tile[ocol + 0][orow]; o.y = tile[ocol + 1][orow];
    o.z = tile[ocol + 2][orow]; o.w = tile[ocol + 3][orow];
    *reinterpret_cast<ushort4*>(dst + (long)(c0 + orow) * 1024 + r0 + ocol) = o;
  }
}

// ============================================================================
// gemm_pi (QKV + score): r11-proven, unchanged. BM=256, BN in {192,256}.
// ============================================================================
template <int SWZ, int BN, bool BIAS, bool VSPLIT, bool EXPSUM>
__global__ __launch_bounds__(512, 2) void gemm_pi(
    const unsigned short* __restrict__ A, const unsigned short* __restrict__ B,
    const float* __restrict__ bias, void* __restrict__ Cout,
    int NT, int lda, int ldb, int ldc,
    long batchA, long batchB, long batchC,
    float* __restrict__ lpart,
    unsigned short* __restrict__ vT) {
  constexpr int WM = 128;
  constexpr int WN = BN / 4;
  constexpr int NF = BN / 64;
  constexpr int BR = BN / 64;
  constexpr int ASH = 256 * 64;
  constexpr int TSH = ASH + BN * 64;
  __shared__ __align__(128) unsigned short lds[2 * TSH];

  int bid = blockIdx.x;
  int b = 0, tm, tn;
  if constexpr (SWZ == 0) {
    int xcd = bid & 7, s = bid >> 3;
    tm = xcd * 4 + (s >> 3); tn = s & 7;
  } else {
    int xcd = bid & 7, s = bid >> 3;
    b = xcd >> 1; tm = (xcd & 1) * 4 + (s >> 3); tn = s & 7;
  }

  int t = threadIdx.x, w = t >> 6, l = t & 63;
  int wr = w >> 2, wc = w & 3;
  int g = l >> 4, c = l & 15;

  f32x4 acc[8][NF];
  #pragma unroll
  for (int m = 0; m < 8; ++m)
    #pragma unroll
    for (int n = 0; n < NF; ++n) acc[m][n] = (f32x4){0.f, 0.f, 0.f, 0.f};

  int srow = t >> 3;
  int scb = (t & 7) * 16;
  const unsigned short* aptr = A + (long)b * batchA + (long)(tm * 256) * lda;
  const unsigned short* bptr = B + (long)b * batchB + (long)(tn * BN) * ldb;
  int kb = scb ^ ((srow & 7) << 4);

  auto stageA = [&](int buf, int k0, int r) {
    int row = r * 64 + srow;
    gload16(aptr + (long)row * lda + k0 + (kb >> 1),
            lds + buf * TSH + r * 4096 + t * 8);
  };
  auto stageB = [&](int buf, int k0, int r) {
    int row = r * 64 + srow;
    gload16(bptr + (long)row * ldb + k0 + (kb >> 1),
            lds + buf * TSH + ASH + r * 4096 + t * 8);
  };
  auto ldA = [&](const char* abase, int mh, int kh, int m) {
    int row = wr * WM + mh * 64 + m * 16 + c;
    int pb = row * 128 + (kh * 32 + g * 8) * 2;
    pb ^= ((pb >> 7) & 7) << 4;
    return *reinterpret_cast<const bf16x8*>(abase + pb);
  };
  auto ldB = [&](const char* bbase, int kh, int n) {
    int row = wc * WN + n * 16 + c;
    int pb = row * 128 + (kh * 32 + g * 8) * 2;
    pb ^= ((pb >> 7) & 7) << 4;
    return *reinterpret_cast<const bf16x8*>(bbase + pb);
  };

  #pragma unroll
  for (int r = 0; r < BR; ++r) stageB(0, 0, r);
  stageA(0, 0, 0); stageA(0, 0, 2); stageA(0, 0, 1); stageA(0, 0, 3);
  asm volatile("s_waitcnt vmcnt(0)" ::: "memory");
  __builtin_amdgcn_s_barrier();

  for (int kt = 0; kt < NT; ++kt) {
    int cur = kt & 1, nb = cur ^ 1;
    const char* abase = (const char*)(lds + cur * TSH);
    const char* bbase = (const char*)(lds + cur * TSH + ASH);
    bool more = (kt + 1) < NT;
    int k1 = (kt + 1) * 64;
    bf16x8 bfr[NF];
    #pragma unroll
    for (int p = 0; p < 4; ++p) {
      const int kh = p >> 1, mh = p & 1;
      bf16x8 af[4];
      #pragma unroll
      for (int m = 0; m < 4; ++m) af[m] = ldA(abase, mh, kh, m);
      if (mh == 0) {
        #pragma unroll
        for (int n = 0; n < NF; ++n) bfr[n] = ldB(bbase, kh, n);
      }
      if (more) {
        if constexpr (BN == 256) {
          if      (p == 0) { stageB(nb, k1, 0); stageB(nb, k1, 1); }
          else if (p == 1) { stageB(nb, k1, 2); stageB(nb, k1, 3); }
          else if (p == 2) { stageA(nb, k1, 0); stageA(nb, k1, 2); }
          else             { stageA(nb, k1, 1); stageA(nb, k1, 3); }
        } else {
          if      (p == 0) { stageB(nb, k1, 0); stageB(nb, k1, 1); stageB(nb, k1, 2); }
          else if (p == 1) { stageA(nb, k1, 0); stageA(nb, k1, 2); }
          else if (p == 2) { stageA(nb, k1, 1); stageA(nb, k1, 3); }
        }
      }
      __builtin_amdgcn_s_barrier();
      asm volatile("s_waitcnt lgkmcnt(0)" ::: "memory");
      __builtin_amdgcn_sched_barrier(0);
      __builtin_amdgcn_s_setprio(1);
      #pragma unroll
      for (int m = 0; m < 4; ++m)
        #pragma unroll
        for (int n = 0; n < NF; ++n)
          acc[mh * 4 + m][n] = MFMA(af[m], bfr[n], acc[mh * 4 + m][n]);
      __builtin_amdgcn_s_setprio(0);
      if (p == 0) {
        if (kt == NT - 1) asm volatile("s_waitcnt vmcnt(0)" ::: "memory");
        else if (BN == 256) asm volatile("s_waitcnt vmcnt(2)" ::: "memory");
        else                asm volatile("s_waitcnt vmcnt(3)" ::: "memory");
      }
      if (p == 3 && more) {
        asm volatile("s_waitcnt vmcnt(2)" ::: "memory");
      }
      __builtin_amdgcn_s_barrier();
    }
  }

  int rbase = tm * 256 + wr * WM + g * 4;
  int c0 = tn * BN + wc * WN + c;

  if constexpr (EXPSUM) {
    __shared__ float lred[4][256];
    #pragma unroll
    for (int mi = 0; mi < 8; ++mi) {
      int roff = (mi / 4) * 64 + (mi % 4) * 16;
      #pragma unroll
      for (int j = 0; j < 4; ++j) {
        long ob = (long)b * batchC + (long)(rbase + roff + j) * ldc + c0;
        float rs = 0.f;
        #pragma unroll
        for (int n = 0; n < NF; ++n) {
          float pv = __expf(acc[mi][n][j] * SCALE);
          ((unsigned short*)Cout)[ob + n * 16] = f2b(pv);
          rs += pv;
        }
        rs += __shfl_xor(rs, 1); rs += __shfl_xor(rs, 2);
        rs += __shfl_xor(rs, 4); rs += __shfl_xor(rs, 8);
        if (c == 0) lred[wc][wr * WM + roff + g * 4 + j] = rs;
      }
    }
    __syncthreads();
    for (int rr = t; rr < 256; rr += 512) {
      float s = lred[0][rr] + lred[1][rr] + lred[2][rr] + lred[3][rr];
      lpart[((long)b * 2048 + tm * 256 + rr) * 8 + tn] = s;
    }
  } else {
    #pragma unroll
    for (int mi = 0; mi < 8; ++mi) {
      int roff = (mi / 4) * 64 + (mi % 4) * 16;
      int s0 = (rbase + roff) & 2047;
      #pragma unroll
      for (int n = 0; n < NF; ++n) {
        int col = c0 + n * 16;
        float bv = BIAS ? bias[col] : 0.f;
        if (VSPLIT && (col - c) >= 512) {
          int bb = tm >> 3;
          ushort4 pk;
          pk.x = f2b(acc[mi][n][0] + bv); pk.y = f2b(acc[mi][n][1] + bv);
          pk.z = f2b(acc[mi][n][2] + bv); pk.w = f2b(acc[mi][n][3] + bv);
          *reinterpret_cast<ushort4*>(vT + (long)bb * 2097152 +
                                      (long)(col - 512) * 2048 + s0) = pk;
        } else {
          long rowb = (long)b * batchC + (long)(rbase + roff) * ldc + col;
          #pragma unroll
          for (int j = 0; j < 4; ++j)
            ((unsigned short*)Cout)[rowb + (long)j * ldc] = f2b(acc[mi][n][j] + bv);
        }
      }
    }
  }
}

// ============================================================================
// gemm_pv (PV): TLP experiment. 1024 threads = 16 waves (4M x 4N), wave tile
// 32x64 -> 4 waves/SIMD (full issue depth) to fill the stalls that r8's
// ping-pong null showed are not role-fillable at 2 waves/SIMD.
// BM=128, BN=256, BK=64, 3-buffer LDS (144KB), stage t+2, 3 loads/thread/
// tile -> vmcnt(3) retires tile t+1 (NT-2 -> 0). 1-barrier/tile (r4 shape).
// ============================================================================
__global__ __launch_bounds__(1024, 4) void gemm_pv(
    const unsigned short* __restrict__ A,   // attn [4][2048][2048] bf16
    const unsigned short* __restrict__ B,   // vT   [4][1024][2048] bf16
    float* __restrict__ Cout,               // out  [4][2048][1024] f32
    const float* __restrict__ linv) {
  constexpr int NT = 32;
  constexpr int ASH = 128 * 64;             // 16KB
  constexpr int TSH = ASH + 256 * 64;       // 48KB
  __shared__ __align__(128) unsigned short lds[3 * TSH];

  int bid = blockIdx.x;                     // 256 = 8 xcd * 32
  int xcd = bid & 7, sidx = bid >> 3;
  int b = xcd >> 1;
  int tm = (xcd & 1) * 8 + (sidx >> 2), tn = sidx & 3;

  int t = threadIdx.x, w = t >> 6, l = t & 63;
  int wr = w >> 2, wc = w & 3;              // 4 x 4 wave grid
  int g = l >> 4, c = l & 15;

  f32x4 acc[2][4];
  #pragma unroll
  for (int m = 0; m < 2; ++m)
    #pragma unroll
    for (int n = 0; n < 4; ++n) acc[m][n] = (f32x4){0.f, 0.f, 0.f, 0.f};

  int srow = t >> 3;                        // 0..127
  int scb = (t & 7) * 16;
  int kb = scb ^ ((srow & 7) << 4);
  const unsigned short* aptr = A + (long)b * 4194304 + (long)(tm * 128) * 2048;
  const unsigned short* bptr = B + (long)b * 2097152 + (long)(tn * 256) * 2048;

  auto stage3 = [&](int buf, int kt2) {     // A: 1 round (128 rows), B: 2
    int k0 = kt2 * 64;
    gload16(aptr + (long)srow * 2048 + k0 + (kb >> 1),
            lds + buf * TSH + t * 8);
    #pragma unroll
    for (int r = 0; r < 2; ++r) {
      int row = r * 128 + srow;
      gload16(bptr + (long)row * 2048 + k0 + (kb >> 1),
              lds + buf * TSH + ASH + r * 8192 + t * 8);
    }
  };

  stage3(0, 0); stage3(1, 1);
  asm volatile("s_waitcnt vmcnt(3)" ::: "memory");
  __builtin_amdgcn_s_barrier();

  for (int kt = 0; kt < NT; ++kt) {
    const char* abase = (const char*)(lds + (kt % 3) * TSH);
    const char* bbase = abase + ASH * 2;

    bf16x8 af[2][2], bf[2][4];
    #pragma unroll
    for (int sk = 0; sk < 2; ++sk) {
      #pragma unroll
      for (int m = 0; m < 2; ++m) {
        int p = (wr * 32 + m * 16 + c) * 128 + (sk * 32 + g * 8) * 2;
        p ^= ((p >> 7) & 7) << 4;
        af[sk][m] = *reinterpret_cast<const bf16x8*>(abase + p);
      }
      #pragma unroll
      for (int n = 0; n < 4; ++n) {
        int p = (wc * 64 + n * 16 + c) * 128 + (sk * 32 + g * 8) * 2;
        p ^= ((p >> 7) & 7) << 4;
        bf[sk][n] = *reinterpret_cast<const bf16x8*>(bbase + p);
      }
    }

    if (kt + 2 < NT) stage3((kt + 2) % 3, kt + 2);

    __builtin_amdgcn_s_setprio(1);
    #pragma unroll
    for (int sk = 0; sk < 2; ++sk)
      #pragma unroll
      for (int m = 0; m < 2; ++m)
        #pragma unroll
        for (int n = 0; n < 4; ++n)
          acc[m][n] = MFMA(af[sk][m], bf[sk][n], acc[m][n]);
    __builtin_amdgcn_s_setprio(0);

    if (kt < NT - 1) {
      if (kt == NT - 2) asm volatile("s_waitcnt vmcnt(0)" ::: "memory");
      else              asm volatile("s_waitcnt vmcnt(3)" ::: "memory");
      __builtin_amdgcn_s_barrier();
    }
  }

  int rbase = tm * 128 + wr * 32 + g * 4;
  int c0 = tn * 256 + wc * 64 + c;
  #pragma unroll
  for (int mi = 0; mi < 2; ++mi) {
    float lv[4];
    #pragma unroll
    for (int j = 0; j < 4; ++j)
      lv[j] = linv[(long)b * 2048 + rbase + mi * 16 + j];
    #pragma unroll
    for (int n = 0; n < 4; ++n) {
      long rowb = (long)b * 2097152 + (long)(rbase + mi * 16) * 1024 + c0 + n * 16;
      #pragma unroll
      for (int j = 0; j < 4; ++j)
        Cout[rowb + (long)j * 1024] = acc[mi][n][j] * lv[j];
    }
  }
}

// ---- 1/rowsum (8 partials per row) -----------------------------------------
__global__ __launch_bounds__(256) void linv_kern(const float* __restrict__ lpart,
                                                 float* __restrict__ linv) {
  int r = blockIdx.x * 256 + threadIdx.x;  // 8192 rows
  float s = 0.f;
  #pragma unroll
  for (int i = 0; i < 8; ++i) s += lpart[(long)r * 8 + i];
  linv[r] = 1.f / s;
}

extern "C" void kernel_launch(void* const* d_in, const int* in_sizes, int n_in,
                              void* d_out, int out_size, void* d_ws, size_t ws_size,
                              hipStream_t stream) {
  (void)in_sizes; (void)n_in; (void)out_size; (void)ws_size;
  const float* x  = (const float*)d_in[0];
  const float* Wq = (const float*)d_in[1];
  const float* bq = (const float*)d_in[2];
  const float* Wk = (const float*)d_in[3];
  const float* bk = (const float*)d_in[4];
  const float* Wv = (const float*)d_in[5];
  const float* bv = (const float*)d_in[6];
  float* out = (float*)d_out;
  char* ws = (char*)d_ws;

  unsigned short* xb   = (unsigned short*)(ws + 0);          // 16,777,216
  float*          lpart= (float*)         (ws + 0);          //    262,144 (overlay)
  float*          linv = (float*)         (ws + 262144);     //     32,768 (overlay)
  unsigned short* wt   = (unsigned short*)(ws + 16777216);   //  3,145,728
  float*          bc   = (float*)         (ws + 19922944);   //      6,144
  unsigned short* qkv  = (unsigned short*)(ws + 19929088);   // 25,165,824
  unsigned short* vT   = (unsigned short*)(ws + 45094912);   // 16,777,216
  unsigned short* attn = (unsigned short*)(ws + 61872128);   // 33,554,432

  // fused prep (convert_x + pack_bias + Wq/Wk/Wv transpose)
  prep_kern<<<4486, 256, 0, stream>>>(x, xb, bq, bk, bv, bc, Wq, Wk, Wv, wt);

  // qkv = xb @ wt^T + bias; V columns stream directly to vT (BN=192, 256 blk)
  gemm_pi<0, 192, true, true, false><<<dim3(256), 512, 0, stream>>>(
      xb, wt, bc, qkv, 16, 1024, 1024, 1536, 0, 0, 0, nullptr, vT);

  // attn = exp(q.k/16) (unnormalized) + row partial sums
  gemm_pi<1, 256, false, false, true><<<dim3(256), 512, 0, stream>>>(
      qkv, qkv + 256, nullptr, attn, 4, 1536, 1536, 2048,
      (long)2048 * 1536, (long)2048 * 1536, (long)2048 * 2048, lpart, nullptr);
  linv_kern<<<32, 256, 0, stream>>>(lpart, linv);

  // out = (attn @ vT^T) * linv  (16-wave TLP variant)
  gemm_pv<<<dim3(256), 1024, 0, stream>>>(attn, vT, out, linv);
}